// Round 4
// baseline (199.936 us; speedup 1.0000x reference)
//
#include <hip/hip_runtime.h>

typedef __attribute__((ext_vector_type(8))) short bf16x8;
typedef __attribute__((ext_vector_type(4))) short s16x4;
typedef __attribute__((ext_vector_type(4))) float f32x4;

#define B_SZ   64
#define CIN    256
#define COUT   256
#define CS     256
#define HIDDEN 64
#define L_SZ   1024
#define LPAD   1026   // l index padded by 1 on each side
#define TEMP   30.0f

// workspace offsets (bytes), all 256-aligned
#define OFF_ATT   0u          // 64*4 floats          = 1 KB
#define OFF_AGGB  1024u       // 64*256 floats        = 64 KB
#define OFF_WAGG  66560u      // 64*3*256*256 bf16    = 25165824 B
#define OFF_XBF   25232384u   // 64*1026*256 bf16     = 33619968 B

__device__ __forceinline__ unsigned short f2bf(float f) {
    union { float f; unsigned int u; } v; v.f = f;
    unsigned int u = v.u;
    return (unsigned short)((u + 0x7fffu + ((u >> 16) & 1u)) >> 16);
}

__device__ __forceinline__ void load_lds16(const unsigned short* g, unsigned short* l) {
    __builtin_amdgcn_global_load_lds(
        (const __attribute__((address_space(1))) unsigned int*)g,
        (__attribute__((address_space(3))) unsigned int*)l, 16, 0, 0);
}

// ---------------------------------------------------------------------------
// Kernel 1: routing MLP -> att (B,4), agg_b (B,256); also zero xbf pad rows.
// ---------------------------------------------------------------------------
__global__ void routing_kernel(const float* __restrict__ cond,
                               const float* __restrict__ w1,
                               const float* __restrict__ w2,
                               const float* __restrict__ bias,
                               float* __restrict__ att_g,
                               float* __restrict__ aggb_g,
                               unsigned short* __restrict__ xbf) {
    __shared__ float cond_s[CS];
    __shared__ float h_s[HIDDEN];
    __shared__ float lg_s[4];
    int t = threadIdx.x;
    int b = blockIdx.x;
    cond_s[t] = cond[b * CS + t];
    xbf[(size_t)b * LPAD * CIN + t] = 0;
    xbf[((size_t)b * LPAD + (LPAD - 1)) * CIN + t] = 0;
    __syncthreads();
    int jj = t >> 2, s = t & 3;
    float p = 0.f;
    const float* w1r = w1 + jj * CS + s * 64;
    const float* cs  = cond_s + s * 64;
    #pragma unroll 16
    for (int c = 0; c < 64; ++c) p += cs[c] * w1r[c];
    p += __shfl_down(p, 2, 4);
    p += __shfl_down(p, 1, 4);
    if (s == 0) h_s[jj] = fmaxf(p, 0.f);
    __syncthreads();
    if (t < 4) {
        float z = 0.f;
        #pragma unroll 16
        for (int h = 0; h < HIDDEN; ++h) z += h_s[h] * w2[t * HIDDEN + h];
        lg_s[t] = z * (1.0f / TEMP);
    }
    __syncthreads();
    float l0 = lg_s[0], l1 = lg_s[1], l2 = lg_s[2], l3 = lg_s[3];
    float mx = fmaxf(fmaxf(l0, l1), fmaxf(l2, l3));
    float e0 = __expf(l0 - mx), e1 = __expf(l1 - mx);
    float e2 = __expf(l2 - mx), e3 = __expf(l3 - mx);
    float inv = 1.0f / (e0 + e1 + e2 + e3);
    float a0 = e0 * inv, a1 = e1 * inv, a2 = e2 * inv, a3 = e3 * inv;
    if (t == 0) {
        att_g[b * 4 + 0] = a0; att_g[b * 4 + 1] = a1;
        att_g[b * 4 + 2] = a2; att_g[b * 4 + 3] = a3;
    }
    aggb_g[b * COUT + t] = a0 * bias[0 * COUT + t] + a1 * bias[1 * COUT + t]
                         + a2 * bias[2 * COUT + t] + a3 * bias[3 * COUT + t];
}

// ---------------------------------------------------------------------------
// Kernel 2: x (B,CIN,L) fp32 -> xbf (B,LPAD,CIN) bf16. float4 reads,
// in-register 4x4 shuffle transpose (xor 16/32), vector LDS, b128 stores.
// grid = (16 l-tiles, 4 i-tiles, 64 b), block = 256
// ---------------------------------------------------------------------------
__global__ void xpose_kernel(const float* __restrict__ x,
                             unsigned short* __restrict__ xbf) {
    __shared__ unsigned short tileB[64 * 68];  // [l][i], stride 68 shorts
    int lt = blockIdx.x, it = blockIdx.y, b = blockIdx.z;
    int t = threadIdx.x;
    int w = t >> 6, lane = t & 63;
    int sub = lane & 15, grp = lane >> 4;

    const float4* xp4 = (const float4*)x;
    // base float4 index for (b, i-row, l-col)
    #pragma unroll
    for (int j = 0; j < 4; ++j) {
        int i_loc = w * 16 + j * 4 + grp;
        float4 v = xp4[((size_t)(b * CIN + it * 64 + i_loc)) * (L_SZ / 4)
                       + lt * 16 + sub];
        // 4x4 transpose across lanes {sub, sub+16, sub+32, sub+48}
        {   // step 1: xor 16 (grp bit0)
            float a = (grp & 1) ? v.x : v.y;
            float c = (grp & 1) ? v.z : v.w;
            float ra = __shfl_xor(a, 16);
            float rc = __shfl_xor(c, 16);
            if (grp & 1) { v.x = ra; v.z = rc; } else { v.y = ra; v.w = rc; }
        }
        {   // step 2: xor 32 (grp bit1)
            float a  = (grp & 2) ? v.x : v.z;
            float b2 = (grp & 2) ? v.y : v.w;
            float ra = __shfl_xor(a, 32);
            float rb = __shfl_xor(b2, 32);
            if (grp & 2) { v.x = ra; v.y = rb; } else { v.z = ra; v.w = rb; }
        }
        // lane now holds i = w*16+j*4+{0..3} at l = lt*64 + sub*4 + grp
        int l_loc = sub * 4 + grp;
        s16x4 pk;
        pk.x = (short)f2bf(v.x); pk.y = (short)f2bf(v.y);
        pk.z = (short)f2bf(v.z); pk.w = (short)f2bf(v.w);
        *(s16x4*)&tileB[l_loc * 68 + w * 16 + j * 4] = pk;
    }
    __syncthreads();
    // write out: rows l_loc, 64 i contiguous (128 B) per row
    int row = t >> 2, c0 = t & 3;
    unsigned short* dst = xbf + ((size_t)b * LPAD + lt * 64 + row + 1) * CIN + it * 64;
    #pragma unroll
    for (int h = 0; h < 2; ++h) {
        int c = c0 + h * 4;
        bf16x8 vv = *(const bf16x8*)&tileB[row * 68 + c * 8];
        *(bf16x8*)&dst[c * 8] = vv;
    }
}

// ---------------------------------------------------------------------------
// Kernel 3: W_agg[b][kh][o][i] = sum_k att[b][k] * weight[k][o][i][kh][1]
// RESTRUCTURED: one block per o (256 blocks). Each thread owns a contiguous
// 8-wide i-chunk for one b and emits ONE bf16x8 (16 B) store per (b,kh) —
// 1.57M stores total vs 12.6M scalar 2-B stores before (store-issue was the
// bottleneck: ~49k store instrs/CU ~= 20 us). Weight staged once per o
// (halves weight re-reads vs the bc-split). Arithmetic per element unchanged.
// ---------------------------------------------------------------------------
__global__ void wagg_kernel(const float* __restrict__ weight,
                            const float* __restrict__ att_g,
                            unsigned short* __restrict__ wagg) {
    __shared__ float w_s[4][2304];
    __shared__ float att_s[256];          // all 64 b x 4 experts
    int o = blockIdx.x;
    int t = threadIdx.x;
    att_s[t] = att_g[t];
    #pragma unroll
    for (int k = 0; k < 4; ++k) {
        const float4* src = (const float4*)(weight + ((size_t)k * COUT + o) * 2304);
        for (int idx = t; idx < 576; idx += 256)
            *(float4*)&w_s[k][idx * 4] = src[idx];
    }
    __syncthreads();
    // tasks: (b, ic) with ic an 8-wide i-chunk; 64*32 = 2048 tasks, 8/thread
    #pragma unroll
    for (int rep = 0; rep < 8; ++rep) {
        int task = rep * 256 + t;
        int b = task >> 5, ic = task & 31;
        float a0 = att_s[b * 4 + 0], a1 = att_s[b * 4 + 1];
        float a2 = att_s[b * 4 + 2], a3 = att_s[b * 4 + 3];
        #pragma unroll
        for (int kh = 0; kh < 3; ++kh) {
            bf16x8 pk;
            #pragma unroll
            for (int j = 0; j < 8; ++j) {
                int off = (ic * 8 + j) * 9 + kh * 3 + 1;
                float v = w_s[0][off] * a0 + w_s[1][off] * a1
                        + w_s[2][off] * a2 + w_s[3][off] * a3;
                pk[j] = (short)f2bf(v);
            }
            *(bf16x8*)&wagg[(((size_t)b * 3 + kh) * COUT + o) * CIN + ic * 8] = pk;
        }
    }
}

// ---------------------------------------------------------------------------
// Kernel 4: per-sample GEMM, XCD-locality swizzle + LDS chunk-XOR swizzle.
// LDS double-buffer with COUNTED-vmcnt pipeline (T3+T4): prefetch tile it+1,
// then s_waitcnt vmcnt(9) waits ONLY for tile it's 9 loads (oldest) — the
// prefetch stays in flight across the MFMA cluster. Raw s_barrier (no
// implicit vmcnt(0) drain, unlike __syncthreads — the round-1/2 bug).
// Per-wave load count made uniform (6 A + 2 B + 1 tail = 9) so the vmcnt
// immediate is wave-independent; tail (B rows 128-129) is issued redundantly
// by all 4 waves with identical data (benign same-value race).
// 128x128 tile, BK=32, 3 kh passes. grid = 1024, block = 256.
// LDS: 2*(24576+8448) = 66048 B -> 2 blocks/CU.
// ---------------------------------------------------------------------------
__global__ __launch_bounds__(256)
void dynconv_gemm(const unsigned short* __restrict__ wagg,
                  const unsigned short* __restrict__ xbf,
                  const float* __restrict__ aggb,
                  float* __restrict__ out) {
    __shared__ unsigned short As[2][3 * 128 * 32];  // 2 x 24576 B
    __shared__ unsigned short Bs[2][132 * 32];      // 2 x 8448 B  (rows 0..129 used)
    int bx = blockIdx.x;
    // XCD swizzle: all 16 blocks of one b land on the same XCD (bx % 8)
    int r8 = bx & 7, s = bx >> 3;
    int tile = s & 15, q = s >> 4;
    int b = r8 + 8 * q;
    int mt = tile & 1, nt = tile >> 1;
    int l0 = nt * 128, m0 = mt * 128;
    int t = threadIdx.x;
    int w = t >> 6, lane = t & 63;
    int ln = lane & 15, hi = lane >> 4;
    int wm = w & 1, wn = w >> 1;
    int jq = lane >> 2, jc = lane & 3;
    int gc = jc ^ ((jq >> 1) & 3);   // chunk-XOR swizzle on global source

    f32x4 acc[4][4];
    #pragma unroll
    for (int a = 0; a < 4; ++a)
        #pragma unroll
        for (int c = 0; c < 4; ++c) acc[a][c] = (f32x4){0.f, 0.f, 0.f, 0.f};

    const unsigned short* wb = wagg + (size_t)b * 3 * COUT * CIN;
    const unsigned short* xb = xbf + (size_t)b * LPAD * CIN;

    // stage K-chunk `it_` into LDS buffer `buf`: exactly 9 loads per wave.
    auto stage_tile = [&](int buf, int it_) {
        int i0 = it_ * 32;
        // A staging: 384 rows (3 kh x 128 m), 16 rows/instr, 6 instr/wave
        #pragma unroll
        for (int si = 0; si < 6; ++si) {
            int inst = w * 6 + si;
            int R = inst * 16 + jq;
            int kh = R >> 7, m = R & 127;
            const unsigned short* g =
                wb + ((size_t)(kh * COUT + m0 + m)) * CIN + i0 + gc * 8;
            load_lds16(g, &As[buf][inst * 512]);
        }
        // B staging rows 0..127: 8 instrs, 2 per wave
        #pragma unroll
        for (int sj = 0; sj < 2; ++sj) {
            int bi = w + sj * 4;
            int r = bi * 16 + jq;
            const unsigned short* g = xb + (size_t)(l0 + r) * CIN + i0 + gc * 8;
            load_lds16(g, &Bs[buf][bi * 512]);
        }
        // tail rows 128..129: all 4 waves issue (uniform vmcnt count), lanes
        // jq<2 active; identical bytes to identical LDS dest — benign.
        {
            int r = 128 + jq;
            if (jq < 2) {
                const unsigned short* g = xb + (size_t)(l0 + r) * CIN + i0 + gc * 8;
                load_lds16(g, &Bs[buf][8 * 512]);
            }
        }
    };

    // prologue: issue tile 0 (9 loads in flight)
    stage_tile(0, 0);

    #pragma unroll
    for (int it = 0; it < 8; ++it) {
        int cur = it & 1;
        if (it < 7) {
            // prefetch next tile, then wait only for the CURRENT tile's loads
            stage_tile(cur ^ 1, it + 1);
            asm volatile("s_waitcnt vmcnt(9)" ::: "memory");
        } else {
            asm volatile("s_waitcnt vmcnt(0)" ::: "memory");
        }
        __builtin_amdgcn_s_barrier();        // all waves: tile `cur` landed
        __builtin_amdgcn_sched_barrier(0);   // pin: no ds_read hoists above
        #pragma unroll
        for (int kh = 0; kh < 3; ++kh) {
            bf16x8 af[4], bfr[4];
            #pragma unroll
            for (int mi = 0; mi < 4; ++mi) {
                int m = wm * 64 + mi * 16 + ln;
                af[mi] = *(const bf16x8*)&As[cur][kh * 4096 + m * 32 + (hi ^ ((m >> 1) & 3)) * 8];
            }
            #pragma unroll
            for (int ni = 0; ni < 4; ++ni) {
                int r = wn * 64 + ni * 16 + ln + kh;
                bfr[ni] = *(const bf16x8*)&Bs[cur][r * 32 + (hi ^ ((r >> 1) & 3)) * 8];
            }
            #pragma unroll
            for (int mi = 0; mi < 4; ++mi)
                #pragma unroll
                for (int ni = 0; ni < 4; ++ni)
                    acc[mi][ni] = __builtin_amdgcn_mfma_f32_16x16x32_bf16(
                        af[mi], bfr[ni], acc[mi][ni], 0, 0, 0);
        }
        __builtin_amdgcn_sched_barrier(0);   // pin: nothing sinks below
        asm volatile("s_waitcnt lgkmcnt(0)" ::: "memory");  // ds_reads drained
        __builtin_amdgcn_s_barrier();        // safe to overwrite buf next iter
    }

    // epilogue: C/D layout col=lane&15 (=l), row=(lane>>4)*4+reg (=o); add bias
    const float* abb = aggb + b * COUT;
    float* ob = out + (size_t)b * COUT * L_SZ;
    #pragma unroll
    for (int mi = 0; mi < 4; ++mi) {
        #pragma unroll
        for (int reg = 0; reg < 4; ++reg) {
            int o = m0 + wm * 64 + mi * 16 + hi * 4 + reg;
            float bv = abb[o];
            #pragma unroll
            for (int ni = 0; ni < 4; ++ni) {
                int l = l0 + wn * 64 + ni * 16 + ln;
                ob[(size_t)o * L_SZ + l] = acc[mi][ni][reg] + bv;
            }
        }
    }
}

extern "C" void kernel_launch(void* const* d_in, const int* in_sizes, int n_in,
                              void* d_out, int out_size, void* d_ws, size_t ws_size,
                              hipStream_t stream) {
    const float* x      = (const float*)d_in[0];
    const float* cond   = (const float*)d_in[1];
    const float* w1     = (const float*)d_in[2];
    const float* w2     = (const float*)d_in[3];
    const float* weight = (const float*)d_in[4];
    const float* bias   = (const float*)d_in[5];
    float* out = (float*)d_out;
    char* ws = (char*)d_ws;
    float* att_g  = (float*)(ws + OFF_ATT);
    float* aggb_g = (float*)(ws + OFF_AGGB);
    unsigned short* wagg = (unsigned short*)(ws + OFF_WAGG);
    unsigned short* xbf  = (unsigned short*)(ws + OFF_XBF);

    routing_kernel<<<64, 256, 0, stream>>>(cond, w1, w2, bias, att_g, aggb_g, xbf);
    xpose_kernel<<<dim3(16, 4, 64), 256, 0, stream>>>(x, xbf);
    wagg_kernel<<<256, 256, 0, stream>>>(weight, att_g, wagg);
    dynconv_gemm<<<1024, 256, 0, stream>>>(wagg, xbf, aggb_g, out);
}

// Round 5
// 176.079 us; speedup vs baseline: 1.1355x; 1.1355x over previous
//
#include <hip/hip_runtime.h>

typedef __attribute__((ext_vector_type(8))) short bf16x8;
typedef __attribute__((ext_vector_type(4))) short s16x4;
typedef __attribute__((ext_vector_type(4))) float f32x4;

#define B_SZ   64
#define CIN    256
#define COUT   256
#define CS     256
#define HIDDEN 64
#define L_SZ   1024
#define LPAD   1026   // l index padded by 1 on each side
#define TEMP   30.0f

// workspace offsets (bytes), all 256-aligned
#define OFF_ATT   0u          // 64*4 floats          = 1 KB
#define OFF_AGGB  1024u       // 64*256 floats        = 64 KB
#define OFF_WAGG  66560u      // 64*3*256*256 bf16    = 25165824 B
#define OFF_XBF   25232384u   // 64*1026*256 bf16     = 33619968 B

__device__ __forceinline__ unsigned short f2bf(float f) {
    union { float f; unsigned int u; } v; v.f = f;
    unsigned int u = v.u;
    return (unsigned short)((u + 0x7fffu + ((u >> 16) & 1u)) >> 16);
}

__device__ __forceinline__ void load_lds16(const unsigned short* g, unsigned short* l) {
    __builtin_amdgcn_global_load_lds(
        (const __attribute__((address_space(1))) unsigned int*)g,
        (__attribute__((address_space(3))) unsigned int*)l, 16, 0, 0);
}

// ---------------------------------------------------------------------------
// Kernel 1: routing MLP -> att (B,4), agg_b (B,256); also zero xbf pad rows.
// ---------------------------------------------------------------------------
__global__ void routing_kernel(const float* __restrict__ cond,
                               const float* __restrict__ w1,
                               const float* __restrict__ w2,
                               const float* __restrict__ bias,
                               float* __restrict__ att_g,
                               float* __restrict__ aggb_g,
                               unsigned short* __restrict__ xbf) {
    __shared__ float cond_s[CS];
    __shared__ float h_s[HIDDEN];
    __shared__ float lg_s[4];
    int t = threadIdx.x;
    int b = blockIdx.x;
    cond_s[t] = cond[b * CS + t];
    xbf[(size_t)b * LPAD * CIN + t] = 0;
    xbf[((size_t)b * LPAD + (LPAD - 1)) * CIN + t] = 0;
    __syncthreads();
    int jj = t >> 2, s = t & 3;
    float p = 0.f;
    const float* w1r = w1 + jj * CS + s * 64;
    const float* cs  = cond_s + s * 64;
    #pragma unroll 16
    for (int c = 0; c < 64; ++c) p += cs[c] * w1r[c];
    p += __shfl_down(p, 2, 4);
    p += __shfl_down(p, 1, 4);
    if (s == 0) h_s[jj] = fmaxf(p, 0.f);
    __syncthreads();
    if (t < 4) {
        float z = 0.f;
        #pragma unroll 16
        for (int h = 0; h < HIDDEN; ++h) z += h_s[h] * w2[t * HIDDEN + h];
        lg_s[t] = z * (1.0f / TEMP);
    }
    __syncthreads();
    float l0 = lg_s[0], l1 = lg_s[1], l2 = lg_s[2], l3 = lg_s[3];
    float mx = fmaxf(fmaxf(l0, l1), fmaxf(l2, l3));
    float e0 = __expf(l0 - mx), e1 = __expf(l1 - mx);
    float e2 = __expf(l2 - mx), e3 = __expf(l3 - mx);
    float inv = 1.0f / (e0 + e1 + e2 + e3);
    float a0 = e0 * inv, a1 = e1 * inv, a2 = e2 * inv, a3 = e3 * inv;
    if (t == 0) {
        att_g[b * 4 + 0] = a0; att_g[b * 4 + 1] = a1;
        att_g[b * 4 + 2] = a2; att_g[b * 4 + 3] = a3;
    }
    aggb_g[b * COUT + t] = a0 * bias[0 * COUT + t] + a1 * bias[1 * COUT + t]
                         + a2 * bias[2 * COUT + t] + a3 * bias[3 * COUT + t];
}

// ---------------------------------------------------------------------------
// Kernel 2: x (B,CIN,L) fp32 -> xbf (B,LPAD,CIN) bf16. float4 reads,
// in-register 4x4 shuffle transpose (xor 16/32), vector LDS, b128 stores.
// grid = (16 l-tiles, 4 i-tiles, 64 b), block = 256
// ---------------------------------------------------------------------------
__global__ void xpose_kernel(const float* __restrict__ x,
                             unsigned short* __restrict__ xbf) {
    __shared__ unsigned short tileB[64 * 68];  // [l][i], stride 68 shorts
    int lt = blockIdx.x, it = blockIdx.y, b = blockIdx.z;
    int t = threadIdx.x;
    int w = t >> 6, lane = t & 63;
    int sub = lane & 15, grp = lane >> 4;

    const float4* xp4 = (const float4*)x;
    // base float4 index for (b, i-row, l-col)
    #pragma unroll
    for (int j = 0; j < 4; ++j) {
        int i_loc = w * 16 + j * 4 + grp;
        float4 v = xp4[((size_t)(b * CIN + it * 64 + i_loc)) * (L_SZ / 4)
                       + lt * 16 + sub];
        // 4x4 transpose across lanes {sub, sub+16, sub+32, sub+48}
        {   // step 1: xor 16 (grp bit0)
            float a = (grp & 1) ? v.x : v.y;
            float c = (grp & 1) ? v.z : v.w;
            float ra = __shfl_xor(a, 16);
            float rc = __shfl_xor(c, 16);
            if (grp & 1) { v.x = ra; v.z = rc; } else { v.y = ra; v.w = rc; }
        }
        {   // step 2: xor 32 (grp bit1)
            float a  = (grp & 2) ? v.x : v.z;
            float b2 = (grp & 2) ? v.y : v.w;
            float ra = __shfl_xor(a, 32);
            float rb = __shfl_xor(b2, 32);
            if (grp & 2) { v.x = ra; v.y = rb; } else { v.z = ra; v.w = rb; }
        }
        // lane now holds i = w*16+j*4+{0..3} at l = lt*64 + sub*4 + grp
        int l_loc = sub * 4 + grp;
        s16x4 pk;
        pk.x = (short)f2bf(v.x); pk.y = (short)f2bf(v.y);
        pk.z = (short)f2bf(v.z); pk.w = (short)f2bf(v.w);
        *(s16x4*)&tileB[l_loc * 68 + w * 16 + j * 4] = pk;
    }
    __syncthreads();
    // write out: rows l_loc, 64 i contiguous (128 B) per row
    int row = t >> 2, c0 = t & 3;
    unsigned short* dst = xbf + ((size_t)b * LPAD + lt * 64 + row + 1) * CIN + it * 64;
    #pragma unroll
    for (int h = 0; h < 2; ++h) {
        int c = c0 + h * 4;
        bf16x8 vv = *(const bf16x8*)&tileB[row * 68 + c * 8];
        *(bf16x8*)&dst[c * 8] = vv;
    }
}

// ---------------------------------------------------------------------------
// Kernel 3: W_agg[b][kh][o][i] = sum_k att[b][k] * weight[k][o][i][kh][1]
// v3: grid (256 o, 2 bc) = 512 blocks (2/CU -> TLP restored, the r4 bug).
// Thread owns a 4-wide i-chunk (ic = t&63) and one wave-sized b-group
// (bg = t>>6). 48 raw weights read from LDS ONCE (register-cached; one-time
// ~0.3us even with the stride-144B 8-way conflict), then 8 b x 3 kh fully
// register-resident FMA + ONE 8-B s16x4 store each. Per store instr a wave
// writes 512 B contiguous (same b,kh across lanes; ic*8B consecutive).
// Arithmetic per element identical to before (sum_k w*a, then round).
// ---------------------------------------------------------------------------
__global__ void wagg_kernel(const float* __restrict__ weight,
                            const float* __restrict__ att_g,
                            unsigned short* __restrict__ wagg) {
    __shared__ float w_s[4][2304];
    __shared__ float att_s[128];
    int o = blockIdx.x, bc = blockIdx.y;
    int t = threadIdx.x;
    if (t < 128) att_s[t] = att_g[bc * 128 + t];
    #pragma unroll
    for (int k = 0; k < 4; ++k) {
        const float4* src = (const float4*)(weight + ((size_t)k * COUT + o) * 2304);
        for (int idx = t; idx < 576; idx += 256)
            *(float4*)&w_s[k][idx * 4] = src[idx];
    }
    __syncthreads();
    int ic = t & 63;    // i = ic*4 + j, j=0..3
    int bg = t >> 6;    // b-group: bb = bg*8 + r, r=0..7 (bb uniform per wave)
    // one-time LDS->reg: raw weights for 4 i x 3 kh x 4 k
    float wv[4][3][4];
    #pragma unroll
    for (int j = 0; j < 4; ++j)
        #pragma unroll
        for (int kh = 0; kh < 3; ++kh)
            #pragma unroll
            for (int k = 0; k < 4; ++k)
                wv[j][kh][k] = w_s[k][(ic * 4 + j) * 9 + kh * 3 + 1];
    #pragma unroll
    for (int r = 0; r < 8; ++r) {
        int bb = bg * 8 + r;
        int b = bc * 32 + bb;
        float a0 = att_s[bb * 4 + 0], a1 = att_s[bb * 4 + 1];
        float a2 = att_s[bb * 4 + 2], a3 = att_s[bb * 4 + 3];
        #pragma unroll
        for (int kh = 0; kh < 3; ++kh) {
            s16x4 pk;
            #pragma unroll
            for (int j = 0; j < 4; ++j) {
                float v = wv[j][kh][0] * a0 + wv[j][kh][1] * a1
                        + wv[j][kh][2] * a2 + wv[j][kh][3] * a3;
                pk[j] = (short)f2bf(v);
            }
            *(s16x4*)&wagg[(((size_t)b * 3 + kh) * COUT + o) * CIN + ic * 4] = pk;
        }
    }
}

// ---------------------------------------------------------------------------
// Kernel 4: per-sample GEMM, XCD-locality swizzle + LDS chunk-XOR swizzle.
// LDS double-buffer with COUNTED-vmcnt pipeline (T3+T4): prefetch tile it+1,
// then s_waitcnt vmcnt(9) waits ONLY for tile it's 9 loads (oldest) — the
// prefetch stays in flight across the MFMA cluster. Raw s_barrier (no
// implicit vmcnt(0) drain). Uniform 9 loads/wave so the vmcnt immediate is
// wave-independent. 128x128 tile, BK=32, 3 kh passes. grid 1024, block 256.
// LDS: 2*(24576+8448) = 66048 B -> 2 blocks/CU.
// ---------------------------------------------------------------------------
__global__ __launch_bounds__(256)
void dynconv_gemm(const unsigned short* __restrict__ wagg,
                  const unsigned short* __restrict__ xbf,
                  const float* __restrict__ aggb,
                  float* __restrict__ out) {
    __shared__ unsigned short As[2][3 * 128 * 32];  // 2 x 24576 B
    __shared__ unsigned short Bs[2][132 * 32];      // 2 x 8448 B  (rows 0..129 used)
    int bx = blockIdx.x;
    // XCD swizzle: all 16 blocks of one b land on the same XCD (bx % 8)
    int r8 = bx & 7, s = bx >> 3;
    int tile = s & 15, q = s >> 4;
    int b = r8 + 8 * q;
    int mt = tile & 1, nt = tile >> 1;
    int l0 = nt * 128, m0 = mt * 128;
    int t = threadIdx.x;
    int w = t >> 6, lane = t & 63;
    int ln = lane & 15, hi = lane >> 4;
    int wm = w & 1, wn = w >> 1;
    int jq = lane >> 2, jc = lane & 3;
    int gc = jc ^ ((jq >> 1) & 3);   // chunk-XOR swizzle on global source

    f32x4 acc[4][4];
    #pragma unroll
    for (int a = 0; a < 4; ++a)
        #pragma unroll
        for (int c = 0; c < 4; ++c) acc[a][c] = (f32x4){0.f, 0.f, 0.f, 0.f};

    const unsigned short* wb = wagg + (size_t)b * 3 * COUT * CIN;
    const unsigned short* xb = xbf + (size_t)b * LPAD * CIN;

    // stage K-chunk `it_` into LDS buffer `buf`: exactly 9 loads per wave.
    auto stage_tile = [&](int buf, int it_) {
        int i0 = it_ * 32;
        // A staging: 384 rows (3 kh x 128 m), 16 rows/instr, 6 instr/wave
        #pragma unroll
        for (int si = 0; si < 6; ++si) {
            int inst = w * 6 + si;
            int R = inst * 16 + jq;
            int kh = R >> 7, m = R & 127;
            const unsigned short* g =
                wb + ((size_t)(kh * COUT + m0 + m)) * CIN + i0 + gc * 8;
            load_lds16(g, &As[buf][inst * 512]);
        }
        // B staging rows 0..127: 8 instrs, 2 per wave
        #pragma unroll
        for (int sj = 0; sj < 2; ++sj) {
            int bi = w + sj * 4;
            int r = bi * 16 + jq;
            const unsigned short* g = xb + (size_t)(l0 + r) * CIN + i0 + gc * 8;
            load_lds16(g, &Bs[buf][bi * 512]);
        }
        // tail rows 128..129: all 4 waves issue (uniform vmcnt count), lanes
        // jq<2 active; identical bytes to identical LDS dest — benign.
        {
            int r = 128 + jq;
            if (jq < 2) {
                const unsigned short* g = xb + (size_t)(l0 + r) * CIN + i0 + gc * 8;
                load_lds16(g, &Bs[buf][8 * 512]);
            }
        }
    };

    // prologue: issue tile 0 (9 loads in flight)
    stage_tile(0, 0);

    #pragma unroll
    for (int it = 0; it < 8; ++it) {
        int cur = it & 1;
        if (it < 7) {
            // prefetch next tile, then wait only for the CURRENT tile's loads
            stage_tile(cur ^ 1, it + 1);
            asm volatile("s_waitcnt vmcnt(9)" ::: "memory");
        } else {
            asm volatile("s_waitcnt vmcnt(0)" ::: "memory");
        }
        __builtin_amdgcn_s_barrier();        // all waves: tile `cur` landed
        __builtin_amdgcn_sched_barrier(0);   // pin: no ds_read hoists above
        #pragma unroll
        for (int kh = 0; kh < 3; ++kh) {
            bf16x8 af[4], bfr[4];
            #pragma unroll
            for (int mi = 0; mi < 4; ++mi) {
                int m = wm * 64 + mi * 16 + ln;
                af[mi] = *(const bf16x8*)&As[cur][kh * 4096 + m * 32 + (hi ^ ((m >> 1) & 3)) * 8];
            }
            #pragma unroll
            for (int ni = 0; ni < 4; ++ni) {
                int r = wn * 64 + ni * 16 + ln + kh;
                bfr[ni] = *(const bf16x8*)&Bs[cur][r * 32 + (hi ^ ((r >> 1) & 3)) * 8];
            }
            #pragma unroll
            for (int mi = 0; mi < 4; ++mi)
                #pragma unroll
                for (int ni = 0; ni < 4; ++ni)
                    acc[mi][ni] = __builtin_amdgcn_mfma_f32_16x16x32_bf16(
                        af[mi], bfr[ni], acc[mi][ni], 0, 0, 0);
        }
        __builtin_amdgcn_sched_barrier(0);   // pin: nothing sinks below
        asm volatile("s_waitcnt lgkmcnt(0)" ::: "memory");  // ds_reads drained
        __builtin_amdgcn_s_barrier();        // safe to overwrite buf next iter
    }

    // epilogue: C/D layout col=lane&15 (=l), row=(lane>>4)*4+reg (=o); add bias
    const float* abb = aggb + b * COUT;
    float* ob = out + (size_t)b * COUT * L_SZ;
    #pragma unroll
    for (int mi = 0; mi < 4; ++mi) {
        #pragma unroll
        for (int reg = 0; reg < 4; ++reg) {
            int o = m0 + wm * 64 + mi * 16 + hi * 4 + reg;
            float bv = abb[o];
            #pragma unroll
            for (int ni = 0; ni < 4; ++ni) {
                int l = l0 + wn * 64 + ni * 16 + ln;
                ob[(size_t)o * L_SZ + l] = acc[mi][ni][reg] + bv;
            }
        }
    }
}

extern "C" void kernel_launch(void* const* d_in, const int* in_sizes, int n_in,
                              void* d_out, int out_size, void* d_ws, size_t ws_size,
                              hipStream_t stream) {
    const float* x      = (const float*)d_in[0];
    const float* cond   = (const float*)d_in[1];
    const float* w1     = (const float*)d_in[2];
    const float* w2     = (const float*)d_in[3];
    const float* weight = (const float*)d_in[4];
    const float* bias   = (const float*)d_in[5];
    float* out = (float*)d_out;
    char* ws = (char*)d_ws;
    float* att_g  = (float*)(ws + OFF_ATT);
    float* aggb_g = (float*)(ws + OFF_AGGB);
    unsigned short* wagg = (unsigned short*)(ws + OFF_WAGG);
    unsigned short* xbf  = (unsigned short*)(ws + OFF_XBF);

    routing_kernel<<<64, 256, 0, stream>>>(cond, w1, w2, bias, att_g, aggb_g, xbf);
    xpose_kernel<<<dim3(16, 4, 64), 256, 0, stream>>>(x, xbf);
    wagg_kernel<<<dim3(256, 2), 256, 0, stream>>>(weight, att_g, wagg);
    dynconv_gemm<<<1024, 256, 0, stream>>>(wagg, xbf, aggb_g, out);
}

// Round 6
// 165.639 us; speedup vs baseline: 1.2071x; 1.0630x over previous
//
#include <hip/hip_runtime.h>

typedef __attribute__((ext_vector_type(8))) short bf16x8;
typedef __attribute__((ext_vector_type(4))) short s16x4;
typedef __attribute__((ext_vector_type(4))) float f32x4;

#define B_SZ   64
#define CIN    256
#define COUT   256
#define CS     256
#define HIDDEN 64
#define L_SZ   1024
#define LPAD   1026   // l index padded by 1 on each side
#define TEMP   30.0f

// workspace offsets (bytes), all 256-aligned
#define OFF_ATT   0u          // 64*4 floats          = 1 KB
#define OFF_AGGB  1024u       // 64*256 floats        = 64 KB
#define OFF_WAGG  66560u      // 64*3*256*256 bf16    = 25165824 B
#define OFF_XBF   25232384u   // 64*1026*256 bf16     = 33619968 B

__device__ __forceinline__ unsigned short f2bf(float f) {
    union { float f; unsigned int u; } v; v.f = f;
    unsigned int u = v.u;
    return (unsigned short)((u + 0x7fffu + ((u >> 16) & 1u)) >> 16);
}

__device__ __forceinline__ void load_lds16(const unsigned short* g, unsigned short* l) {
    __builtin_amdgcn_global_load_lds(
        (const __attribute__((address_space(1))) unsigned int*)g,
        (__attribute__((address_space(3))) unsigned int*)l, 16, 0, 0);
}

// ---------------------------------------------------------------------------
// Kernel 1: routing MLP -> att (B,4), agg_b (B,256); also zero xbf pad rows.
// ---------------------------------------------------------------------------
__global__ void routing_kernel(const float* __restrict__ cond,
                               const float* __restrict__ w1,
                               const float* __restrict__ w2,
                               const float* __restrict__ bias,
                               float* __restrict__ att_g,
                               float* __restrict__ aggb_g,
                               unsigned short* __restrict__ xbf) {
    __shared__ float cond_s[CS];
    __shared__ float h_s[HIDDEN];
    __shared__ float lg_s[4];
    int t = threadIdx.x;
    int b = blockIdx.x;
    cond_s[t] = cond[b * CS + t];
    xbf[(size_t)b * LPAD * CIN + t] = 0;
    xbf[((size_t)b * LPAD + (LPAD - 1)) * CIN + t] = 0;
    __syncthreads();
    int jj = t >> 2, s = t & 3;
    float p = 0.f;
    const float* w1r = w1 + jj * CS + s * 64;
    const float* cs  = cond_s + s * 64;
    #pragma unroll 16
    for (int c = 0; c < 64; ++c) p += cs[c] * w1r[c];
    p += __shfl_down(p, 2, 4);
    p += __shfl_down(p, 1, 4);
    if (s == 0) h_s[jj] = fmaxf(p, 0.f);
    __syncthreads();
    if (t < 4) {
        float z = 0.f;
        #pragma unroll 16
        for (int h = 0; h < HIDDEN; ++h) z += h_s[h] * w2[t * HIDDEN + h];
        lg_s[t] = z * (1.0f / TEMP);
    }
    __syncthreads();
    float l0 = lg_s[0], l1 = lg_s[1], l2 = lg_s[2], l3 = lg_s[3];
    float mx = fmaxf(fmaxf(l0, l1), fmaxf(l2, l3));
    float e0 = __expf(l0 - mx), e1 = __expf(l1 - mx);
    float e2 = __expf(l2 - mx), e3 = __expf(l3 - mx);
    float inv = 1.0f / (e0 + e1 + e2 + e3);
    float a0 = e0 * inv, a1 = e1 * inv, a2 = e2 * inv, a3 = e3 * inv;
    if (t == 0) {
        att_g[b * 4 + 0] = a0; att_g[b * 4 + 1] = a1;
        att_g[b * 4 + 2] = a2; att_g[b * 4 + 3] = a3;
    }
    aggb_g[b * COUT + t] = a0 * bias[0 * COUT + t] + a1 * bias[1 * COUT + t]
                         + a2 * bias[2 * COUT + t] + a3 * bias[3 * COUT + t];
}

// ---------------------------------------------------------------------------
// Kernel 2 (FUSED prep): block-role split.
//   blocks [0,512):    wagg role — W_agg[b][kh][o][i] = sum_k att[b][k]*w[...]
//                      direct-global weight reads (12 dwords/thread, i=t,
//                      conflict-free r3 mapping), att staged in 512 B LDS,
//                      128 B/wave contiguous stores. No weight LDS => LDS
//                      footprint stays 8.7 KB so xpose keeps 8 blocks/CU.
//   blocks [512,4608): xpose role — x (B,CIN,L) fp32 -> xbf (B,LPAD,CIN)
//                      bf16, in-register 4x4 shuffle transpose (unchanged).
// Rationale: the two are independent (wagg needs att only; xpose needs x
// only) and were serializing ~16 + ~21-25 us; wagg is latency-shaped with
// idle pipes (r4: VALUBusy~0), xpose is BW-shaped — co-residency hides one
// under the other. wagg blocks issued FIRST so their long-latency loads
// overlap the xpose wave ramp.
// ---------------------------------------------------------------------------
__global__ __launch_bounds__(256)
void prep_kernel(const float* __restrict__ x,
                 const float* __restrict__ weight,
                 const float* __restrict__ att_g,
                 unsigned short* __restrict__ xbf,
                 unsigned short* __restrict__ wagg) {
    __shared__ unsigned short smem[64 * 68];   // 8704 B, role-dependent view
    int bid = blockIdx.x;
    int t = threadIdx.x;

    if (bid < 512) {
        // ---------------- wagg role ----------------
        float* att_s = (float*)smem;           // 128 floats = 512 B
        int o = bid & 255, bc = bid >> 8;
        if (t < 128) att_s[t] = att_g[bc * 128 + t];
        __syncthreads();
        // direct global reads: thread owns i = t; 4 experts x 3 kh (kw=1)
        float wv[3][4];
        #pragma unroll
        for (int k = 0; k < 4; ++k) {
            const float* p = weight + (((size_t)k * COUT + o) * CIN + t) * 9;
            #pragma unroll
            for (int kh = 0; kh < 3; ++kh)
                wv[kh][k] = p[kh * 3 + 1];
        }
        for (int bb = 0; bb < 32; ++bb) {
            int b = bc * 32 + bb;
            float a0 = att_s[bb * 4 + 0], a1 = att_s[bb * 4 + 1];
            float a2 = att_s[bb * 4 + 2], a3 = att_s[bb * 4 + 3];
            #pragma unroll
            for (int kh = 0; kh < 3; ++kh) {
                float v = wv[kh][0] * a0 + wv[kh][1] * a1
                        + wv[kh][2] * a2 + wv[kh][3] * a3;
                wagg[(((size_t)b * 3 + kh) * COUT + o) * CIN + t] = f2bf(v);
            }
        }
    } else {
        // ---------------- xpose role ----------------
        unsigned short* tileB = smem;          // [l][i], stride 68 shorts
        int r = bid - 512;
        int lt = r & 15, it = (r >> 4) & 3, b = r >> 6;
        int w = t >> 6, lane = t & 63;
        int sub = lane & 15, grp = lane >> 4;

        const float4* xp4 = (const float4*)x;
        #pragma unroll
        for (int j = 0; j < 4; ++j) {
            int i_loc = w * 16 + j * 4 + grp;
            float4 v = xp4[((size_t)(b * CIN + it * 64 + i_loc)) * (L_SZ / 4)
                           + lt * 16 + sub];
            {   // step 1: xor 16 (grp bit0)
                float a = (grp & 1) ? v.x : v.y;
                float c = (grp & 1) ? v.z : v.w;
                float ra = __shfl_xor(a, 16);
                float rc = __shfl_xor(c, 16);
                if (grp & 1) { v.x = ra; v.z = rc; } else { v.y = ra; v.w = rc; }
            }
            {   // step 2: xor 32 (grp bit1)
                float a  = (grp & 2) ? v.x : v.z;
                float b2 = (grp & 2) ? v.y : v.w;
                float ra = __shfl_xor(a, 32);
                float rb = __shfl_xor(b2, 32);
                if (grp & 2) { v.x = ra; v.y = rb; } else { v.z = ra; v.w = rb; }
            }
            int l_loc = sub * 4 + grp;
            s16x4 pk;
            pk.x = (short)f2bf(v.x); pk.y = (short)f2bf(v.y);
            pk.z = (short)f2bf(v.z); pk.w = (short)f2bf(v.w);
            *(s16x4*)&tileB[l_loc * 68 + w * 16 + j * 4] = pk;
        }
        __syncthreads();
        int row = t >> 2, c0 = t & 3;
        unsigned short* dst = xbf + ((size_t)b * LPAD + lt * 64 + row + 1) * CIN + it * 64;
        #pragma unroll
        for (int h = 0; h < 2; ++h) {
            int c = c0 + h * 4;
            bf16x8 vv = *(const bf16x8*)&tileB[row * 68 + c * 8];
            *(bf16x8*)&dst[c * 8] = vv;
        }
    }
}

// ---------------------------------------------------------------------------
// Kernel 4: per-sample GEMM, XCD-locality swizzle + LDS chunk-XOR swizzle.
// LDS double-buffer with COUNTED-vmcnt pipeline (T3+T4): prefetch tile it+1,
// then s_waitcnt vmcnt(9) waits ONLY for tile it's 9 loads (oldest) — the
// prefetch stays in flight across the MFMA cluster. Raw s_barrier (no
// implicit vmcnt(0) drain). Uniform 9 loads/wave so the vmcnt immediate is
// wave-independent. 128x128 tile, BK=32, 3 kh passes. grid 1024, block 256.
// LDS: 2*(24576+8448) = 66048 B -> 2 blocks/CU.
// ---------------------------------------------------------------------------
__global__ __launch_bounds__(256)
void dynconv_gemm(const unsigned short* __restrict__ wagg,
                  const unsigned short* __restrict__ xbf,
                  const float* __restrict__ aggb,
                  float* __restrict__ out) {
    __shared__ unsigned short As[2][3 * 128 * 32];  // 2 x 24576 B
    __shared__ unsigned short Bs[2][132 * 32];      // 2 x 8448 B  (rows 0..129 used)
    int bx = blockIdx.x;
    // XCD swizzle: all 16 blocks of one b land on the same XCD (bx % 8)
    int r8 = bx & 7, s = bx >> 3;
    int tile = s & 15, q = s >> 4;
    int b = r8 + 8 * q;
    int mt = tile & 1, nt = tile >> 1;
    int l0 = nt * 128, m0 = mt * 128;
    int t = threadIdx.x;
    int w = t >> 6, lane = t & 63;
    int ln = lane & 15, hi = lane >> 4;
    int wm = w & 1, wn = w >> 1;
    int jq = lane >> 2, jc = lane & 3;
    int gc = jc ^ ((jq >> 1) & 3);   // chunk-XOR swizzle on global source

    f32x4 acc[4][4];
    #pragma unroll
    for (int a = 0; a < 4; ++a)
        #pragma unroll
        for (int c = 0; c < 4; ++c) acc[a][c] = (f32x4){0.f, 0.f, 0.f, 0.f};

    const unsigned short* wb = wagg + (size_t)b * 3 * COUT * CIN;
    const unsigned short* xb = xbf + (size_t)b * LPAD * CIN;

    // stage K-chunk `it_` into LDS buffer `buf`: exactly 9 loads per wave.
    auto stage_tile = [&](int buf, int it_) {
        int i0 = it_ * 32;
        // A staging: 384 rows (3 kh x 128 m), 16 rows/instr, 6 instr/wave
        #pragma unroll
        for (int si = 0; si < 6; ++si) {
            int inst = w * 6 + si;
            int R = inst * 16 + jq;
            int kh = R >> 7, m = R & 127;
            const unsigned short* g =
                wb + ((size_t)(kh * COUT + m0 + m)) * CIN + i0 + gc * 8;
            load_lds16(g, &As[buf][inst * 512]);
        }
        // B staging rows 0..127: 8 instrs, 2 per wave
        #pragma unroll
        for (int sj = 0; sj < 2; ++sj) {
            int bi = w + sj * 4;
            int r = bi * 16 + jq;
            const unsigned short* g = xb + (size_t)(l0 + r) * CIN + i0 + gc * 8;
            load_lds16(g, &Bs[buf][bi * 512]);
        }
        // tail rows 128..129: all 4 waves issue (uniform vmcnt count), lanes
        // jq<2 active; identical bytes to identical LDS dest — benign.
        {
            int r = 128 + jq;
            if (jq < 2) {
                const unsigned short* g = xb + (size_t)(l0 + r) * CIN + i0 + gc * 8;
                load_lds16(g, &Bs[buf][8 * 512]);
            }
        }
    };

    // prologue: issue tile 0 (9 loads in flight)
    stage_tile(0, 0);

    #pragma unroll
    for (int it = 0; it < 8; ++it) {
        int cur = it & 1;
        if (it < 7) {
            // prefetch next tile, then wait only for the CURRENT tile's loads
            stage_tile(cur ^ 1, it + 1);
            asm volatile("s_waitcnt vmcnt(9)" ::: "memory");
        } else {
            asm volatile("s_waitcnt vmcnt(0)" ::: "memory");
        }
        __builtin_amdgcn_s_barrier();        // all waves: tile `cur` landed
        __builtin_amdgcn_sched_barrier(0);   // pin: no ds_read hoists above
        #pragma unroll
        for (int kh = 0; kh < 3; ++kh) {
            bf16x8 af[4], bfr[4];
            #pragma unroll
            for (int mi = 0; mi < 4; ++mi) {
                int m = wm * 64 + mi * 16 + ln;
                af[mi] = *(const bf16x8*)&As[cur][kh * 4096 + m * 32 + (hi ^ ((m >> 1) & 3)) * 8];
            }
            #pragma unroll
            for (int ni = 0; ni < 4; ++ni) {
                int r = wn * 64 + ni * 16 + ln + kh;
                bfr[ni] = *(const bf16x8*)&Bs[cur][r * 32 + (hi ^ ((r >> 1) & 3)) * 8];
            }
            #pragma unroll
            for (int mi = 0; mi < 4; ++mi)
                #pragma unroll
                for (int ni = 0; ni < 4; ++ni)
                    acc[mi][ni] = __builtin_amdgcn_mfma_f32_16x16x32_bf16(
                        af[mi], bfr[ni], acc[mi][ni], 0, 0, 0);
        }
        __builtin_amdgcn_sched_barrier(0);   // pin: nothing sinks below
        asm volatile("s_waitcnt lgkmcnt(0)" ::: "memory");  // ds_reads drained
        __builtin_amdgcn_s_barrier();        // safe to overwrite buf next iter
    }

    // epilogue: C/D layout col=lane&15 (=l), row=(lane>>4)*4+reg (=o); add bias
    const float* abb = aggb + b * COUT;
    float* ob = out + (size_t)b * COUT * L_SZ;
    #pragma unroll
    for (int mi = 0; mi < 4; ++mi) {
        #pragma unroll
        for (int reg = 0; reg < 4; ++reg) {
            int o = m0 + wm * 64 + mi * 16 + hi * 4 + reg;
            float bv = abb[o];
            #pragma unroll
            for (int ni = 0; ni < 4; ++ni) {
                int l = l0 + wn * 64 + ni * 16 + ln;
                ob[(size_t)o * L_SZ + l] = acc[mi][ni][reg] + bv;
            }
        }
    }
}

extern "C" void kernel_launch(void* const* d_in, const int* in_sizes, int n_in,
                              void* d_out, int out_size, void* d_ws, size_t ws_size,
                              hipStream_t stream) {
    const float* x      = (const float*)d_in[0];
    const float* cond   = (const float*)d_in[1];
    const float* w1     = (const float*)d_in[2];
    const float* w2     = (const float*)d_in[3];
    const float* weight = (const float*)d_in[4];
    const float* bias   = (const float*)d_in[5];
    float* out = (float*)d_out;
    char* ws = (char*)d_ws;
    float* att_g  = (float*)(ws + OFF_ATT);
    float* aggb_g = (float*)(ws + OFF_AGGB);
    unsigned short* wagg = (unsigned short*)(ws + OFF_WAGG);
    unsigned short* xbf  = (unsigned short*)(ws + OFF_XBF);

    routing_kernel<<<64, 256, 0, stream>>>(cond, w1, w2, bias, att_g, aggb_g, xbf);
    prep_kernel<<<4608, 256, 0, stream>>>(x, weight, att_g, xbf, wagg);
    dynconv_gemm<<<1024, 256, 0, stream>>>(wagg, xbf, aggb_g, out);
}